// Round 2
// baseline (996.646 us; speedup 1.0000x reference)
//
#include <hip/hip_runtime.h>
#include <hip/hip_bf16.h>
#include <stdint.h>

// N = 4096 throughout. fp32 I/O, bf16 MFMA compute.
#define NN 4096

typedef __attribute__((ext_vector_type(8))) short   short8;
typedef __attribute__((ext_vector_type(8))) __bf16  bf16x8;
typedef __attribute__((ext_vector_type(4))) float   f32x4;

__device__ __forceinline__ uint16_t f2bf(float f) {
  uint32_t u = __float_as_uint(f);
  u += 0x7fff + ((u >> 16) & 1);   // RNE (finite inputs only)
  return (uint16_t)(u >> 16);
}
__device__ __forceinline__ uint32_t pack2(float a, float b) {
  return (uint32_t)f2bf(a) | ((uint32_t)f2bf(b) << 16);
}

// async global->LDS, 16B per lane. LDS dest: wave-uniform base + lane*16.
__device__ __forceinline__ void gl_lds16(const void* g, void* l) {
  __builtin_amdgcn_global_load_lds(
      (__attribute__((address_space(1))) void*)g,
      (__attribute__((address_space(3))) void*)l, 16, 0, 0);
}

// ---------------------------------------------------------------------------
// S^T = (X+Y)^T, D^T = (X-Y)^T : fp32 in, bf16 out, 64x64 tiles through LDS.
// ---------------------------------------------------------------------------
__global__ __launch_bounds__(256)
void tp_sumdiff(const float* __restrict__ X, const float* __restrict__ Y,
                uint16_t* __restrict__ S, uint16_t* __restrict__ D, int jbase) {
  __shared__ uint16_t sS[64][66];   // +2 shorts pad
  __shared__ uint16_t sD[64][66];
  const int t   = threadIdx.x;
  const int j0l = blockIdx.x * 64;              // local col within panel
  const int k0  = blockIdx.y * 64;
  const int r   = t >> 2;
  const int c   = (t & 3) * 16;
  const size_t goff = (size_t)(k0 + r) * NN + jbase + j0l + c;
  const float4* px = (const float4*)(X + goff);
  const float4* py = (const float4*)(Y + goff);
#pragma unroll
  for (int i = 0; i < 4; ++i) {
    const float4 vx = px[i];
    const float4 vy = py[i];
    sS[r][c + 4*i]     = f2bf(vx.x + vy.x);
    sS[r][c + 4*i + 1] = f2bf(vx.y + vy.y);
    sS[r][c + 4*i + 2] = f2bf(vx.z + vy.z);
    sS[r][c + 4*i + 3] = f2bf(vx.w + vy.w);
    sD[r][c + 4*i]     = f2bf(vx.x - vy.x);
    sD[r][c + 4*i + 1] = f2bf(vx.y - vy.y);
    sD[r][c + 4*i + 2] = f2bf(vx.z - vy.z);
    sD[r][c + 4*i + 3] = f2bf(vx.w - vy.w);
  }
  __syncthreads();
  const int jj = t >> 2;
  const int kc = (t & 3) * 16;
  uint32_t vs[8], vd[8];
#pragma unroll
  for (int i = 0; i < 8; ++i) {
    vs[i] = (uint32_t)sS[kc + 2*i][jj] | ((uint32_t)sS[kc + 2*i + 1][jj] << 16);
    vd[i] = (uint32_t)sD[kc + 2*i][jj] | ((uint32_t)sD[kc + 2*i + 1][jj] << 16);
  }
  const size_t ooff = (size_t)(j0l + jj) * NN + k0 + kc;  // local row in panel
  uint4* ps = (uint4*)(S + ooff);
  uint4* pd = (uint4*)(D + ooff);
  ps[0] = make_uint4(vs[0], vs[1], vs[2], vs[3]);
  ps[1] = make_uint4(vs[4], vs[5], vs[6], vs[7]);
  pd[0] = make_uint4(vd[0], vd[1], vd[2], vd[3]);
  pd[1] = make_uint4(vd[4], vd[5], vd[6], vd[7]);
}

// ---------------------------------------------------------------------------
// W (fp32) -> bf16 RNE, row-major. Memory-bound one-shot.
// ---------------------------------------------------------------------------
__global__ __launch_bounds__(256)
void wcvt(const float* __restrict__ W, uint16_t* __restrict__ Wb) {
  const size_t base = ((size_t)blockIdx.x * 256 + threadIdx.x) * 8;
  const float4 v0 = *(const float4*)(W + base);
  const float4 v1 = *(const float4*)(W + base + 4);
  *(uint4*)(Wb + base) = make_uint4(pack2(v0.x, v0.y), pack2(v0.z, v0.w),
                                    pack2(v1.x, v1.y), pack2(v1.z, v1.w));
}

// ---------------------------------------------------------------------------
// Shared epilogues. C/D frag: col = lane&15, row = (lane>>4)*4 + reg.
// ---------------------------------------------------------------------------
__device__ __forceinline__ void epi_write(const f32x4 (&accS)[4][4], const f32x4 (&accD)[4][4],
                                          float* __restrict__ outU, float* __restrict__ outL,
                                          int i0, int j0, int jbase,
                                          int wm, int wn, int lr, int q) {
#pragma unroll
  for (int f = 0; f < 4; ++f)
#pragma unroll
    for (int g = 0; g < 4; ++g) {
      const int col = jbase + j0 + wn + g * 16 + lr;
#pragma unroll
      for (int r = 0; r < 4; ++r) {
        const int row = i0 + wm + f * 16 + q * 4 + r;
        const float s = accS[f][g][r], d = accD[f][g][r];
        outU[(size_t)row * NN + col] = (s + d) * 0.5f;
        outL[(size_t)row * NN + col] = (s - d) * 0.5f;
      }
    }
}

__device__ __forceinline__ void epi_reduce(const f32x4 (&accS)[4][4], const f32x4 (&accD)[4][4],
                                           const float* __restrict__ pub, const float* __restrict__ plb,
                                           float* __restrict__ accUv, float* __restrict__ accLv,
                                           int i0, int j0, int jbase,
                                           int wm, int wn, int lr, int q) {
  float uv[4], lv[4];
#pragma unroll
  for (int g = 0; g < 4; ++g) {
    const int col = jbase + j0 + wn + g * 16 + lr;
    uv[g] = pub[col];
    lv[g] = plb[col];
  }
  float su[16], sl[16];
#pragma unroll
  for (int f = 0; f < 4; ++f)
#pragma unroll
    for (int r = 0; r < 4; ++r) {
      float au = 0.f, al = 0.f;
#pragma unroll
      for (int g = 0; g < 4; ++g) {
        const float s  = accS[f][g][r], d = accD[f][g][r];
        const float wu = (s + d) * 0.5f;
        const float wl = (s - d) * 0.5f;
        au += fmaxf(wu, 0.f) * uv[g] + fminf(wu, 0.f) * lv[g];
        al += fmaxf(wl, 0.f) * lv[g] + fminf(wl, 0.f) * uv[g];
      }
      su[f * 4 + r] = au;
      sl[f * 4 + r] = al;
    }
#pragma unroll
  for (int m = 1; m < 16; m <<= 1)
#pragma unroll
    for (int p = 0; p < 16; ++p) {
      su[p] += __shfl_xor(su[p], m, 64);
      sl[p] += __shfl_xor(sl[p], m, 64);
    }
  const int row = i0 + wm + (lr >> 2) * 16 + q * 4 + (lr & 3);
  atomicAdd(&accUv[row], su[lr]);
  atomicAdd(&accLv[row], sl[lr]);
}

// ---------------------------------------------------------------------------
// FAST PATH dual GEMM, 8-phase counted-vmcnt schedule (T3+T4+T5, m201-style).
//   accS = W @ Bsum,  accD = |W| @ Bdiff.   A is bf16 in global (Wbf).
// Geometry: BM=256, BN=128, BK=32; 512 thr = 8 waves (4M x 2N), 64x64/wave.
// LDS: 4-slot ring x 32KB (A 16K | Bs 8K | Bd 8K), prefetch distance 3.
// Per K-tile 2 phases (16 S-MFMAs, 16 D-MFMAs); vmcnt(8) once per tile ->
// tiles t+2,t+3 stay in flight across barriers (never drains to 0 mid-loop).
// Raw s_barrier with "memory" clobber: no vmcnt drain, but compiler cannot
// move ds_reads / gl_lds issues across slot-safety boundaries.
// ---------------------------------------------------------------------------
template <int MODE>
__global__ __launch_bounds__(512, 2)
void gemm8p(const uint16_t* __restrict__ Ab,
            const uint16_t* __restrict__ Bs,
            const uint16_t* __restrict__ Bd,
            float* __restrict__ outU, float* __restrict__ outL,
            const float* __restrict__ pub, const float* __restrict__ plb,
            float* __restrict__ accUv, float* __restrict__ accLv, int jbase) {
  __shared__ __align__(16) uint16_t sm[4 * 16384];   // 128 KB

  const int tid  = threadIdx.x;
  const int lane = tid & 63;
  const int wv   = tid >> 6;

  // bijective XCD swizzle: nwg % 8 == 0 in all launches here
  const int gx  = (int)gridDim.x;
  const int nwg = gx * (int)gridDim.y;
  const int raw = (int)blockIdx.y * gx + (int)blockIdx.x;
  const int id  = (raw & 7) * (nwg >> 3) + (raw >> 3);
  const int i0  = (id / gx) * 256;     // global rows
  const int j0  = (id % gx) * 128;     // local cols within panel

  const int wm = (wv >> 1) * 64;       // wave row offset (4 m-waves)
  const int wn = (wv & 1) * 64;        // wave col offset (2 n-waves)
  const int lr = lane & 15;
  const int q  = lane >> 4;

  f32x4 accS[4][4], accD[4][4];
#pragma unroll
  for (int f = 0; f < 4; ++f)
#pragma unroll
    for (int g = 0; g < 4; ++g) {
      accS[f][g] = f32x4{0.f, 0.f, 0.f, 0.f};
      accD[f][g] = f32x4{0.f, 0.f, 0.f, 0.f};
    }

  // staging source offsets (shorts). One gl_lds = 512 thr x 16B = 8KB.
  const uint32_t colc = (uint32_t)(tid & 3) * 8;
  const uint32_t rA0  = (uint32_t)(i0 + (tid >> 2)) * NN + colc;        // rows 0-127
  const uint32_t rA1  = rA0 + 128u * NN;                                 // rows 128-255
  const uint32_t rB   = (uint32_t)(j0 + (tid >> 2)) * NN + colc;        // 128 rows

  // wave-uniform LDS short-offsets within a slot
  const int lA0 = wv * 512;
  const int lA1 = 4096  + wv * 512;
  const int lBs = 8192  + wv * 512;
  const int lBd = 12288 + wv * 512;

  const short8 msk = {0x7fff,0x7fff,0x7fff,0x7fff,0x7fff,0x7fff,0x7fff,0x7fff};

  // prologue: issue tiles 0..2 (12 loads), ensure tile 0 landed (vmcnt 8)
#pragma unroll
  for (int t0 = 0; t0 < 3; ++t0) {
    uint16_t* ns = sm + t0 * 16384;
    const uint32_t kn = (uint32_t)t0 * 32;
    gl_lds16(Ab + rA0 + kn, ns + lA0);
    gl_lds16(Ab + rA1 + kn, ns + lA1);
    gl_lds16(Bs + rB  + kn, ns + lBs);
    gl_lds16(Bd + rB  + kn, ns + lBd);
  }
  asm volatile("s_waitcnt vmcnt(8)" ::: "memory");
  asm volatile("s_barrier" ::: "memory");

  for (int t = 0; t < 128; ++t) {
    const uint16_t* sl = sm + (t & 3) * 16384;
    const bool pf = (t + 3 < 128);
    uint16_t* ns = sm + ((t + 3) & 3) * 16384;   // slot freed at tile t-1
    const uint32_t kn = (uint32_t)(t + 3) * 32;

    // ---- phase A : S chain -------------------------------------------
    bf16x8 a[4], bsf[4];
#pragma unroll
    for (int f = 0; f < 4; ++f)
      a[f] = __builtin_bit_cast(bf16x8,
             *(const short8*)(sl + (wm + f * 16 + lr) * 32 + q * 8));
#pragma unroll
    for (int g = 0; g < 4; ++g)
      bsf[g] = __builtin_bit_cast(bf16x8,
               *(const short8*)(sl + 8192 + (wn + g * 16 + lr) * 32 + q * 8));
    if (pf) {
      gl_lds16(Ab + rA0 + kn, ns + lA0);
      gl_lds16(Ab + rA1 + kn, ns + lA1);
    }
    asm volatile("s_barrier" ::: "memory");
    __builtin_amdgcn_s_setprio(1);
#pragma unroll
    for (int g = 0; g < 4; ++g)
#pragma unroll
      for (int f = 0; f < 4; ++f)
        accS[f][g] = __builtin_amdgcn_mfma_f32_16x16x32_bf16(a[f], bsf[g], accS[f][g], 0, 0, 0);
    __builtin_amdgcn_s_setprio(0);
    asm volatile("s_barrier" ::: "memory");

    // ---- phase B : D chain -------------------------------------------
    bf16x8 aa[4], bdf[4];
#pragma unroll
    for (int f = 0; f < 4; ++f)
      aa[f] = __builtin_bit_cast(bf16x8,
              (short8)(__builtin_bit_cast(short8, a[f]) & msk));   // |W|
#pragma unroll
    for (int g = 0; g < 4; ++g)
      bdf[g] = __builtin_bit_cast(bf16x8,
               *(const short8*)(sl + 12288 + (wn + g * 16 + lr) * 32 + q * 8));
    if (pf) {
      gl_lds16(Bs + rB + kn, ns + lBs);
      gl_lds16(Bd + rB + kn, ns + lBd);
    }
    // end-of-tile wait: tile t+1 must be resident; keep t+2,t+3 in flight
    if (pf)            asm volatile("s_waitcnt vmcnt(8)" ::: "memory");
    else if (t == 125) asm volatile("s_waitcnt vmcnt(4)" ::: "memory");
    else if (t == 126) asm volatile("s_waitcnt vmcnt(0)" ::: "memory");
    asm volatile("s_barrier" ::: "memory");
    __builtin_amdgcn_s_setprio(1);
#pragma unroll
    for (int g = 0; g < 4; ++g)
#pragma unroll
      for (int f = 0; f < 4; ++f)
        accD[f][g] = __builtin_amdgcn_mfma_f32_16x16x32_bf16(aa[f], bdf[g], accD[f][g], 0, 0, 0);
    __builtin_amdgcn_s_setprio(0);
    asm volatile("s_barrier" ::: "memory");
  }

  if (MODE == 0) {
    epi_write(accS, accD, outU, outL, i0, j0, jbase, wm, wn, lr, q);
  } else {
    epi_reduce(accS, accD, pub, plb, accUv, accLv, i0, j0, jbase, wm, wn, lr, q);
  }
}

// ---------------------------------------------------------------------------
// FALLBACK dual GEMM (small ws): fp32 A converted during staging; 128² tile.
// ---------------------------------------------------------------------------
template <int MODE>
__global__ __launch_bounds__(256, 2)
void gemm_fused(const float* __restrict__ Wg,
                const uint16_t* __restrict__ Bs,
                const uint16_t* __restrict__ Bd,
                float* __restrict__ outU, float* __restrict__ outL,
                const float* __restrict__ pub, const float* __restrict__ plb,
                float* __restrict__ accUv, float* __restrict__ accLv, int jbase) {
  __shared__ __align__(16) uint16_t sA [128 * 32];
  __shared__ __align__(16) uint16_t sBs[128 * 32];
  __shared__ __align__(16) uint16_t sBd[128 * 32];

  const int tid  = threadIdx.x;
  const int lane = tid & 63;
  const int wv   = tid >> 6;
  const int i0   = blockIdx.y * 128;
  const int j0   = blockIdx.x * 128;
  const int wm   = (wv >> 1) * 64;
  const int wn   = (wv & 1) * 64;
  const int lr   = lane & 15;
  const int q    = lane >> 4;

  f32x4 accS[4][4], accD[4][4];
#pragma unroll
  for (int f = 0; f < 4; ++f)
#pragma unroll
    for (int g = 0; g < 4; ++g) {
      accS[f][g] = f32x4{0.f, 0.f, 0.f, 0.f};
      accD[f][g] = f32x4{0.f, 0.f, 0.f, 0.f};
    }

  const int e0 = tid, e1 = tid + 256;
  const size_t ga0 = (size_t)(i0 + (e0 >> 2)) * NN + (e0 & 3) * 8;  // floats
  const size_t ga1 = (size_t)(i0 + (e1 >> 2)) * NN + (e1 & 3) * 8;
  const size_t gb0 = (size_t)(j0 + (e0 >> 2)) * NN + (e0 & 3) * 8;  // shorts
  const size_t gb1 = (size_t)(j0 + (e1 >> 2)) * NN + (e1 & 3) * 8;

  uint16_t* lS0 = sBs + wv * 512;
  uint16_t* lS1 = sBs + 2048 + wv * 512;
  uint16_t* lD0 = sBd + wv * 512;
  uint16_t* lD1 = sBd + 2048 + wv * 512;

  const short8 msk = {0x7fff,0x7fff,0x7fff,0x7fff,0x7fff,0x7fff,0x7fff,0x7fff};

  for (int kk = 0; kk < NN; kk += 32) {
    const float4 a00 = *(const float4*)(Wg + ga0 + kk);
    const float4 a01 = *(const float4*)(Wg + ga0 + kk + 4);
    const float4 a10 = *(const float4*)(Wg + ga1 + kk);
    const float4 a11 = *(const float4*)(Wg + ga1 + kk + 4);
    const uint4 wA0 = make_uint4(pack2(a00.x, a00.y), pack2(a00.z, a00.w),
                                 pack2(a01.x, a01.y), pack2(a01.z, a01.w));
    const uint4 wA1 = make_uint4(pack2(a10.x, a10.y), pack2(a10.z, a10.w),
                                 pack2(a11.x, a11.y), pack2(a11.z, a11.w));
    __syncthreads();
    gl_lds16(Bs + gb0 + kk, lS0);
    gl_lds16(Bs + gb1 + kk, lS1);
    gl_lds16(Bd + gb0 + kk, lD0);
    gl_lds16(Bd + gb1 + kk, lD1);
    *(uint4*)(sA + e0 * 8) = wA0;
    *(uint4*)(sA + e1 * 8) = wA1;
    __syncthreads();

    bf16x8 a[4], aa[4];
#pragma unroll
    for (int f = 0; f < 4; ++f) {
      short8 as = *(const short8*)(sA + (wm + f * 16 + lr) * 32 + q * 8);
      a[f]  = __builtin_bit_cast(bf16x8, as);
      aa[f] = __builtin_bit_cast(bf16x8, (short8)(as & msk));
    }
#pragma unroll
    for (int g = 0; g < 4; ++g) {
      bf16x8 bs = *(const bf16x8*)(sBs + (wn + g * 16 + lr) * 32 + q * 8);
      bf16x8 bd = *(const bf16x8*)(sBd + (wn + g * 16 + lr) * 32 + q * 8);
#pragma unroll
      for (int f = 0; f < 4; ++f) {
        accS[f][g] = __builtin_amdgcn_mfma_f32_16x16x32_bf16(a[f],  bs, accS[f][g], 0, 0, 0);
        accD[f][g] = __builtin_amdgcn_mfma_f32_16x16x32_bf16(aa[f], bd, accD[f][g], 0, 0, 0);
      }
    }
  }

  if (MODE == 0) {
    epi_write(accS, accD, outU, outL, i0, j0, jbase, wm, wn, lr, q);
  } else {
    epi_reduce(accS, accD, pub, plb, accUv, accLv, i0, j0, jbase, wm, wn, lr, q);
  }
}

// ---------------------------------------------------------------------------
// Six fused matvecs in one read of W (fp32).
// ---------------------------------------------------------------------------
__device__ __forceinline__ void load16(const float* p, float* f) {
  const float4* q4 = (const float4*)p;
#pragma unroll
  for (int i = 0; i < 4; ++i) {
    const float4 v = q4[i];
    f[4*i] = v.x; f[4*i+1] = v.y; f[4*i+2] = v.z; f[4*i+3] = v.w;
  }
}

__global__ __launch_bounds__(256)
void matvec6(const float* __restrict__ Wg, const float* __restrict__ bvec,
             const float* __restrict__ pbu,  const float* __restrict__ pbl,
             const float* __restrict__ pbu2, const float* __restrict__ pbl2,
             const float* __restrict__ pub,  const float* __restrict__ plb,
             float* __restrict__ out_bu, float* __restrict__ out_bl,
             float* __restrict__ bounds,
             float* __restrict__ bu_f, float* __restrict__ bl_f) {
  const int row = blockIdx.x;
  const int t   = threadIdx.x;
  const int c0  = t * 16;
  float w[16], xu[16], xl[16], x2u[16], x2l[16], uu[16], ul[16];
  load16(Wg + (size_t)row * NN + c0, w);
  load16(pbu  + c0, xu);  load16(pbl  + c0, xl);
  load16(pbu2 + c0, x2u); load16(pbl2 + c0, x2l);
  load16(pub  + c0, uu);  load16(plb  + c0, ul);
  float a_bu = 0, a_bl = 0, a_ub = 0, a_lb = 0, a_2u = 0, a_2l = 0;
#pragma unroll
  for (int i = 0; i < 16; ++i) {
    const float wp = fmaxf(w[i], 0.f), wm = fminf(w[i], 0.f);
    a_bu += wp * xu[i]  + wm * xl[i];
    a_bl += wp * xl[i]  + wm * xu[i];
    a_ub += wp * uu[i]  + wm * ul[i];
    a_lb += wp * ul[i]  + wm * uu[i];
    a_2u += wp * x2u[i] + wm * x2l[i];
    a_2l += wp * x2l[i] + wm * x2u[i];
  }
#pragma unroll
  for (int off = 32; off; off >>= 1) {
    a_bu += __shfl_down(a_bu, off, 64);
    a_bl += __shfl_down(a_bl, off, 64);
    a_ub += __shfl_down(a_ub, off, 64);
    a_lb += __shfl_down(a_lb, off, 64);
    a_2u += __shfl_down(a_2u, off, 64);
    a_2l += __shfl_down(a_2l, off, 64);
  }
  __shared__ float red[4][6];
  const int lane = t & 63, wvv = t >> 6;
  if (lane == 0) {
    red[wvv][0] = a_bu; red[wvv][1] = a_bl; red[wvv][2] = a_ub;
    red[wvv][3] = a_lb; red[wvv][4] = a_2u; red[wvv][5] = a_2l;
  }
  __syncthreads();
  if (t == 0) {
    float r0=0, r1=0, r2=0, r3=0, r4=0, r5=0;
    for (int v = 0; v < 4; ++v) {
      r0 += red[v][0]; r1 += red[v][1]; r2 += red[v][2];
      r3 += red[v][3]; r4 += red[v][4]; r5 += red[v][5];
    }
    const float bb = bvec[row];
    out_bu[row]      = r0 + bb;
    out_bl[row]      = r1 + bb;
    bounds[row]      = r2 + bb;   // ub
    bounds[NN + row] = r3 + bb;   // lb
    bu_f[row]        = r4 + bb;
    bl_f[row]        = r5 + bb;
  }
}

// ---------------------------------------------------------------------------
__global__ __launch_bounds__(256)
void finalize_bounds(const float* __restrict__ accU, const float* __restrict__ accL,
                     const float* __restrict__ bu_f, const float* __restrict__ bl_f,
                     float* __restrict__ bounds) {
  const int i = blockIdx.x * 256 + threadIdx.x;
  if (i >= NN) return;
  const float ub  = bounds[i];
  const float lb  = bounds[NN + i];
  const float ub2 = accU[i] + bu_f[i];
  const float lb2 = accL[i] + bl_f[i];
  bounds[2 * NN + i] = fminf(ub, ub2);
  bounds[3 * NN + i] = fmaxf(lb, lb2);
}

// ---------------------------------------------------------------------------
extern "C" void kernel_launch(void* const* d_in, const int* in_sizes, int n_in,
                              void* d_out, int out_size, void* d_ws, size_t ws_size,
                              hipStream_t stream) {
  const float* W    = (const float*)d_in[0];
  const float* b    = (const float*)d_in[1];
  const float* pWu  = (const float*)d_in[2];
  const float* pWl  = (const float*)d_in[3];
  const float* pbu  = (const float*)d_in[4];
  const float* pbl  = (const float*)d_in[5];
  const float* pWu2 = (const float*)d_in[6];
  const float* pWl2 = (const float*)d_in[7];
  const float* pbu2 = (const float*)d_in[8];
  const float* pbl2 = (const float*)d_in[9];
  const float* pub  = (const float*)d_in[10];
  const float* plb  = (const float*)d_in[11];

  float* out    = (float*)d_out;
  float* bounds = out;                          // [4, N]
  float* Wup    = out + 4 * NN;                 // [N, N]
  float* Wlo    = Wup + (size_t)NN * NN;        // [N, N]
  float* b_up   = Wlo + (size_t)NN * NN;        // [N]
  float* b_lo   = b_up + NN;                    // [N]

  // --- small ws header: 64 KB ---
  float* accU = (float*)d_ws;                   // N fp32
  float* accL = accU + NN;
  float* bu_f = accL + NN;
  float* bl_f = bu_f + NN;
  const size_t hdr = 65536;
  const size_t WBF = (size_t)NN * NN;           // elements of bf16 W

  (void)hipMemsetAsync(accU, 0, 2 * NN * sizeof(float), stream);

  // Fast path: ws holds Wbf (bf16 W, 32 MB) + S/D panels. Pick smallest P.
  int Pf = 1;
  while (Pf < 32 && hdr + 2 * WBF + 2 * ((size_t)NN / Pf) * NN * 2 > ws_size) Pf *= 2;
  const bool fast = (hdr + 2 * WBF + 2 * ((size_t)NN / Pf) * NN * 2 <= ws_size);

  if (fast) {
    uint16_t* Wbf = (uint16_t*)((char*)d_ws + hdr);
    const int NPf = NN / Pf;
    uint16_t* Sp = Wbf + WBF;
    uint16_t* Dp = Sp + (size_t)NPf * NN;

    wcvt<<<dim3(8192), 256, 0, stream>>>(W, Wbf);

    // --- GEMM2: bf16 scratch in d_out's Wup/Wlo regions (overwritten later)
    tp_sumdiff<<<dim3(64, 64), 256, 0, stream>>>(pWu2, pWl2,
                                                 (uint16_t*)Wup, (uint16_t*)Wlo, 0);
    gemm8p<1><<<dim3(32, 16), 512, 0, stream>>>(Wbf, (uint16_t*)Wup, (uint16_t*)Wlo,
                                                nullptr, nullptr,
                                                pub, plb, accU, accL, 0);

    // --- GEMM1: panelized over columns, scratch in ws after Wbf ---
    for (int p = 0; p < Pf; ++p) {
      const int jb = p * NPf;
      tp_sumdiff<<<dim3(NPf / 64, 64), 256, 0, stream>>>(pWu, pWl, Sp, Dp, jb);
      gemm8p<0><<<dim3(NPf / 128, 16), 512, 0, stream>>>(Wbf, Sp, Dp, Wup, Wlo,
                                                         nullptr, nullptr,
                                                         nullptr, nullptr, jb);
    }
  } else {
    // Fallback: fp32-A staging path; panels sized to fit ws.
    int P = 1;
    while (P < 32 && hdr + 2 * ((size_t)NN / P) * NN * 2 > ws_size) P *= 2;
    const int NP = NN / P;
    uint16_t* big = (uint16_t*)((char*)d_ws + hdr);
    uint16_t* Sp = big;
    uint16_t* Dp = big + (size_t)NP * NN;

    tp_sumdiff<<<dim3(64, 64), 256, 0, stream>>>(pWu2, pWl2,
                                                 (uint16_t*)Wup, (uint16_t*)Wlo, 0);
    gemm_fused<1><<<dim3(32, 32), 256, 0, stream>>>(W, (uint16_t*)Wup, (uint16_t*)Wlo,
                                                    nullptr, nullptr,
                                                    pub, plb, accU, accL, 0);
    for (int p = 0; p < P; ++p) {
      const int jb = p * NP;
      tp_sumdiff<<<dim3(NP / 64, 64), 256, 0, stream>>>(pWu, pWl, Sp, Dp, jb);
      gemm_fused<0><<<dim3(NP / 128, 32), 256, 0, stream>>>(W, Sp, Dp, Wup, Wlo,
                                                            nullptr, nullptr,
                                                            nullptr, nullptr, jb);
    }
  }

  matvec6<<<NN, 256, 0, stream>>>(W, b, pbu, pbl, pbu2, pbl2, pub, plb,
                                  b_up, b_lo, bounds, bu_f, bl_f);
  finalize_bounds<<<16, 256, 0, stream>>>(accU, accL, bu_f, bl_f, bounds);
}

// Round 3
// 942.372 us; speedup vs baseline: 1.0576x; 1.0576x over previous
//
#include <hip/hip_runtime.h>
#include <hip/hip_bf16.h>
#include <stdint.h>

// N = 4096 throughout. fp32 I/O, bf16 MFMA compute.
#define NN 4096

typedef __attribute__((ext_vector_type(8))) short   short8;
typedef __attribute__((ext_vector_type(8))) __bf16  bf16x8;
typedef __attribute__((ext_vector_type(4))) float   f32x4;

__device__ __forceinline__ uint16_t f2bf(float f) {
  uint32_t u = __float_as_uint(f);
  u += 0x7fff + ((u >> 16) & 1);   // RNE (finite inputs only)
  return (uint16_t)(u >> 16);
}
__device__ __forceinline__ uint32_t pack2(float a, float b) {
  return (uint32_t)f2bf(a) | ((uint32_t)f2bf(b) << 16);
}

// async global->LDS, 16B per lane. LDS dest: wave-uniform base + lane*16.
__device__ __forceinline__ void gl_lds16(const void* g, void* l) {
  __builtin_amdgcn_global_load_lds(
      (__attribute__((address_space(1))) void*)g,
      (__attribute__((address_space(3))) void*)l, 16, 0, 0);
}

// ---------------------------------------------------------------------------
// S^T = (X+Y)^T, D^T = (X-Y)^T : fp32 in, bf16 out, 64x64 tiles through LDS.
// ---------------------------------------------------------------------------
__global__ __launch_bounds__(256)
void tp_sumdiff(const float* __restrict__ X, const float* __restrict__ Y,
                uint16_t* __restrict__ S, uint16_t* __restrict__ D, int jbase) {
  __shared__ uint16_t sS[64][66];   // +2 shorts pad
  __shared__ uint16_t sD[64][66];
  const int t   = threadIdx.x;
  const int j0l = blockIdx.x * 64;              // local col within panel
  const int k0  = blockIdx.y * 64;
  const int r   = t >> 2;
  const int c   = (t & 3) * 16;
  const size_t goff = (size_t)(k0 + r) * NN + jbase + j0l + c;
  const float4* px = (const float4*)(X + goff);
  const float4* py = (const float4*)(Y + goff);
#pragma unroll
  for (int i = 0; i < 4; ++i) {
    const float4 vx = px[i];
    const float4 vy = py[i];
    sS[r][c + 4*i]     = f2bf(vx.x + vy.x);
    sS[r][c + 4*i + 1] = f2bf(vx.y + vy.y);
    sS[r][c + 4*i + 2] = f2bf(vx.z + vy.z);
    sS[r][c + 4*i + 3] = f2bf(vx.w + vy.w);
    sD[r][c + 4*i]     = f2bf(vx.x - vy.x);
    sD[r][c + 4*i + 1] = f2bf(vx.y - vy.y);
    sD[r][c + 4*i + 2] = f2bf(vx.z - vy.z);
    sD[r][c + 4*i + 3] = f2bf(vx.w - vy.w);
  }
  __syncthreads();
  const int jj = t >> 2;
  const int kc = (t & 3) * 16;
  uint32_t vs[8], vd[8];
#pragma unroll
  for (int i = 0; i < 8; ++i) {
    vs[i] = (uint32_t)sS[kc + 2*i][jj] | ((uint32_t)sS[kc + 2*i + 1][jj] << 16);
    vd[i] = (uint32_t)sD[kc + 2*i][jj] | ((uint32_t)sD[kc + 2*i + 1][jj] << 16);
  }
  const size_t ooff = (size_t)(j0l + jj) * NN + k0 + kc;  // local row in panel
  uint4* ps = (uint4*)(S + ooff);
  uint4* pd = (uint4*)(D + ooff);
  ps[0] = make_uint4(vs[0], vs[1], vs[2], vs[3]);
  ps[1] = make_uint4(vs[4], vs[5], vs[6], vs[7]);
  pd[0] = make_uint4(vd[0], vd[1], vd[2], vd[3]);
  pd[1] = make_uint4(vd[4], vd[5], vd[6], vd[7]);
}

// ---------------------------------------------------------------------------
// W (fp32) -> bf16 RNE, row-major. Memory-bound one-shot.
// ---------------------------------------------------------------------------
__global__ __launch_bounds__(256)
void wcvt(const float* __restrict__ W, uint16_t* __restrict__ Wb) {
  const size_t base = ((size_t)blockIdx.x * 256 + threadIdx.x) * 8;
  const float4 v0 = *(const float4*)(W + base);
  const float4 v1 = *(const float4*)(W + base + 4);
  *(uint4*)(Wb + base) = make_uint4(pack2(v0.x, v0.y), pack2(v0.z, v0.w),
                                    pack2(v1.x, v1.y), pack2(v1.z, v1.w));
}

// ---------------------------------------------------------------------------
// Shared epilogues. C/D frag: col = lane&15, row = (lane>>4)*4 + reg.
// ---------------------------------------------------------------------------
__device__ __forceinline__ void epi_write(const f32x4 (&accS)[4][4], const f32x4 (&accD)[4][4],
                                          float* __restrict__ outU, float* __restrict__ outL,
                                          int i0, int j0, int jbase,
                                          int wm, int wn, int lr, int q) {
#pragma unroll
  for (int f = 0; f < 4; ++f)
#pragma unroll
    for (int g = 0; g < 4; ++g) {
      const int col = jbase + j0 + wn + g * 16 + lr;
#pragma unroll
      for (int r = 0; r < 4; ++r) {
        const int row = i0 + wm + f * 16 + q * 4 + r;
        const float s = accS[f][g][r], d = accD[f][g][r];
        outU[(size_t)row * NN + col] = (s + d) * 0.5f;
        outL[(size_t)row * NN + col] = (s - d) * 0.5f;
      }
    }
}

__device__ __forceinline__ void epi_reduce(const f32x4 (&accS)[4][4], const f32x4 (&accD)[4][4],
                                           const float* __restrict__ pub, const float* __restrict__ plb,
                                           float* __restrict__ accUv, float* __restrict__ accLv,
                                           int i0, int j0, int jbase,
                                           int wm, int wn, int lr, int q) {
  float uv[4], lv[4];
#pragma unroll
  for (int g = 0; g < 4; ++g) {
    const int col = jbase + j0 + wn + g * 16 + lr;
    uv[g] = pub[col];
    lv[g] = plb[col];
  }
  float su[16], sl[16];
#pragma unroll
  for (int f = 0; f < 4; ++f)
#pragma unroll
    for (int r = 0; r < 4; ++r) {
      float au = 0.f, al = 0.f;
#pragma unroll
      for (int g = 0; g < 4; ++g) {
        const float s  = accS[f][g][r], d = accD[f][g][r];
        const float wu = (s + d) * 0.5f;
        const float wl = (s - d) * 0.5f;
        au += fmaxf(wu, 0.f) * uv[g] + fminf(wu, 0.f) * lv[g];
        al += fmaxf(wl, 0.f) * lv[g] + fminf(wl, 0.f) * uv[g];
      }
      su[f * 4 + r] = au;
      sl[f * 4 + r] = al;
    }
#pragma unroll
  for (int m = 1; m < 16; m <<= 1)
#pragma unroll
    for (int p = 0; p < 16; ++p) {
      su[p] += __shfl_xor(su[p], m, 64);
      sl[p] += __shfl_xor(sl[p], m, 64);
    }
  const int row = i0 + wm + (lr >> 2) * 16 + q * 4 + (lr & 3);
  atomicAdd(&accUv[row], su[lr]);
  atomicAdd(&accLv[row], sl[lr]);
}

// ---------------------------------------------------------------------------
// FAST PATH dual GEMM, 8-phase counted-vmcnt schedule + T2 chunk swizzle.
//   accS = W @ Bsum,  accD = |W| @ Bdiff.   A is bf16 in global (Wbf).
// Geometry: BM=256, BN=128, BK=32; 512 thr = 8 waves (4M x 2N), 64x64/wave.
// LDS: 4-slot ring x 32KB (A 16K | Bs 8K | Bd 8K), prefetch distance 3.
// Bank-conflict fix (rule #21 both-sides): LDS dest stays LINEAR (gl_lds
// requirement); the global SOURCE 16B-chunk column is pre-permuted
// c' = c ^ ((row>>1)&3), and the ds_read applies the same XOR — which is a
// per-lane CONSTANT ((q ^ ((lr>>1)&3))*8), zero extra VALU in the loop.
// 16 consecutive rows then span 8 distinct 4-bank slots -> 2-way -> free.
// vmcnt(8) once per tile: tiles t+2,t+3 stay in flight across barriers.
// ---------------------------------------------------------------------------
template <int MODE>
__global__ __launch_bounds__(512, 2)
void gemm8p(const uint16_t* __restrict__ Ab,
            const uint16_t* __restrict__ Bs,
            const uint16_t* __restrict__ Bd,
            float* __restrict__ outU, float* __restrict__ outL,
            const float* __restrict__ pub, const float* __restrict__ plb,
            float* __restrict__ accUv, float* __restrict__ accLv, int jbase) {
  __shared__ __align__(16) uint16_t sm[4 * 16384];   // 128 KB

  const int tid  = threadIdx.x;
  const int lane = tid & 63;
  const int wv   = tid >> 6;

  // identity block mapping (XCD swizzle regressed FETCH 3x in R1)
  const int i0 = (int)blockIdx.y * 256;     // global rows
  const int j0 = (int)blockIdx.x * 128;     // local cols within panel

  const int wm = (wv >> 1) * 64;       // wave row offset (4 m-waves)
  const int wn = (wv & 1) * 64;        // wave col offset (2 n-waves)
  const int lr = lane & 15;
  const int q  = lane >> 4;
  // per-lane swizzled chunk offset for all frag reads (shorts)
  const int ql = ((q ^ ((lr >> 1) & 3)) * 8);

  f32x4 accS[4][4], accD[4][4];
#pragma unroll
  for (int f = 0; f < 4; ++f)
#pragma unroll
    for (int g = 0; g < 4; ++g) {
      accS[f][g] = f32x4{0.f, 0.f, 0.f, 0.f};
      accD[f][g] = f32x4{0.f, 0.f, 0.f, 0.f};
    }

  // staging source offsets (shorts). One gl_lds = 512 thr x 16B = 8KB.
  // source chunk col pre-swizzled: c' = (tid&3) ^ ((row>>1)&3), row = tid>>2.
  const uint32_t colc = (uint32_t)(((tid & 3) ^ ((tid >> 3) & 3)) * 8);
  const uint32_t rA0  = (uint32_t)(i0 + (tid >> 2)) * NN + colc;        // rows 0-127
  const uint32_t rA1  = rA0 + 128u * NN;   // rows 128-255 (row+128: swz unchanged)
  const uint32_t rB   = (uint32_t)(j0 + (tid >> 2)) * NN + colc;        // 128 rows

  // wave-uniform LDS short-offsets within a slot
  const int lA0 = wv * 512;
  const int lA1 = 4096  + wv * 512;
  const int lBs = 8192  + wv * 512;
  const int lBd = 12288 + wv * 512;

  const short8 msk = {0x7fff,0x7fff,0x7fff,0x7fff,0x7fff,0x7fff,0x7fff,0x7fff};

  // prologue: issue tiles 0..2 (12 loads), ensure tile 0 landed (vmcnt 8)
#pragma unroll
  for (int t0 = 0; t0 < 3; ++t0) {
    uint16_t* ns = sm + t0 * 16384;
    const uint32_t kn = (uint32_t)t0 * 32;
    gl_lds16(Ab + rA0 + kn, ns + lA0);
    gl_lds16(Ab + rA1 + kn, ns + lA1);
    gl_lds16(Bs + rB  + kn, ns + lBs);
    gl_lds16(Bd + rB  + kn, ns + lBd);
  }
  asm volatile("s_waitcnt vmcnt(8)" ::: "memory");
  asm volatile("s_barrier" ::: "memory");

  for (int t = 0; t < 128; ++t) {
    const uint16_t* sl = sm + (t & 3) * 16384;
    const bool pf = (t + 3 < 128);
    uint16_t* ns = sm + ((t + 3) & 3) * 16384;   // slot freed at tile t-1
    const uint32_t kn = (uint32_t)(t + 3) * 32;

    // ---- phase A : S chain -------------------------------------------
    bf16x8 a[4], bsf[4];
#pragma unroll
    for (int f = 0; f < 4; ++f)
      a[f] = __builtin_bit_cast(bf16x8,
             *(const short8*)(sl + (wm + f * 16 + lr) * 32 + ql));
#pragma unroll
    for (int g = 0; g < 4; ++g)
      bsf[g] = __builtin_bit_cast(bf16x8,
               *(const short8*)(sl + 8192 + (wn + g * 16 + lr) * 32 + ql));
    if (pf) {
      gl_lds16(Ab + rA0 + kn, ns + lA0);
      gl_lds16(Ab + rA1 + kn, ns + lA1);
    }
    asm volatile("s_barrier" ::: "memory");
    __builtin_amdgcn_s_setprio(1);
#pragma unroll
    for (int g = 0; g < 4; ++g)
#pragma unroll
      for (int f = 0; f < 4; ++f)
        accS[f][g] = __builtin_amdgcn_mfma_f32_16x16x32_bf16(a[f], bsf[g], accS[f][g], 0, 0, 0);
    __builtin_amdgcn_s_setprio(0);
    asm volatile("s_barrier" ::: "memory");

    // ---- phase B : D chain -------------------------------------------
    bf16x8 aa[4], bdf[4];
#pragma unroll
    for (int f = 0; f < 4; ++f)
      aa[f] = __builtin_bit_cast(bf16x8,
              (short8)(__builtin_bit_cast(short8, a[f]) & msk));   // |W|
#pragma unroll
    for (int g = 0; g < 4; ++g)
      bdf[g] = __builtin_bit_cast(bf16x8,
               *(const short8*)(sl + 12288 + (wn + g * 16 + lr) * 32 + ql));
    if (pf) {
      gl_lds16(Bs + rB + kn, ns + lBs);
      gl_lds16(Bd + rB + kn, ns + lBd);
    }
    // end-of-tile wait: tile t+1 must be resident; keep t+2,t+3 in flight
    if (pf)            asm volatile("s_waitcnt vmcnt(8)" ::: "memory");
    else if (t == 125) asm volatile("s_waitcnt vmcnt(4)" ::: "memory");
    else if (t == 126) asm volatile("s_waitcnt vmcnt(0)" ::: "memory");
    asm volatile("s_barrier" ::: "memory");
    __builtin_amdgcn_s_setprio(1);
#pragma unroll
    for (int g = 0; g < 4; ++g)
#pragma unroll
      for (int f = 0; f < 4; ++f)
        accD[f][g] = __builtin_amdgcn_mfma_f32_16x16x32_bf16(aa[f], bdf[g], accD[f][g], 0, 0, 0);
    __builtin_amdgcn_s_setprio(0);
    asm volatile("s_barrier" ::: "memory");
  }

  if (MODE == 0) {
    epi_write(accS, accD, outU, outL, i0, j0, jbase, wm, wn, lr, q);
  } else {
    epi_reduce(accS, accD, pub, plb, accUv, accLv, i0, j0, jbase, wm, wn, lr, q);
  }
}

// ---------------------------------------------------------------------------
// FALLBACK dual GEMM (small ws): fp32 A converted during staging; 128² tile.
// ---------------------------------------------------------------------------
template <int MODE>
__global__ __launch_bounds__(256, 2)
void gemm_fused(const float* __restrict__ Wg,
                const uint16_t* __restrict__ Bs,
                const uint16_t* __restrict__ Bd,
                float* __restrict__ outU, float* __restrict__ outL,
                const float* __restrict__ pub, const float* __restrict__ plb,
                float* __restrict__ accUv, float* __restrict__ accLv, int jbase) {
  __shared__ __align__(16) uint16_t sA [128 * 32];
  __shared__ __align__(16) uint16_t sBs[128 * 32];
  __shared__ __align__(16) uint16_t sBd[128 * 32];

  const int tid  = threadIdx.x;
  const int lane = tid & 63;
  const int wv   = tid >> 6;
  const int i0   = blockIdx.y * 128;
  const int j0   = blockIdx.x * 128;
  const int wm   = (wv >> 1) * 64;
  const int wn   = (wv & 1) * 64;
  const int lr   = lane & 15;
  const int q    = lane >> 4;

  f32x4 accS[4][4], accD[4][4];
#pragma unroll
  for (int f = 0; f < 4; ++f)
#pragma unroll
    for (int g = 0; g < 4; ++g) {
      accS[f][g] = f32x4{0.f, 0.f, 0.f, 0.f};
      accD[f][g] = f32x4{0.f, 0.f, 0.f, 0.f};
    }

  const int e0 = tid, e1 = tid + 256;
  const size_t ga0 = (size_t)(i0 + (e0 >> 2)) * NN + (e0 & 3) * 8;  // floats
  const size_t ga1 = (size_t)(i0 + (e1 >> 2)) * NN + (e1 & 3) * 8;
  const size_t gb0 = (size_t)(j0 + (e0 >> 2)) * NN + (e0 & 3) * 8;  // shorts
  const size_t gb1 = (size_t)(j0 + (e1 >> 2)) * NN + (e1 & 3) * 8;

  uint16_t* lS0 = sBs + wv * 512;
  uint16_t* lS1 = sBs + 2048 + wv * 512;
  uint16_t* lD0 = sBd + wv * 512;
  uint16_t* lD1 = sBd + 2048 + wv * 512;

  const short8 msk = {0x7fff,0x7fff,0x7fff,0x7fff,0x7fff,0x7fff,0x7fff,0x7fff};

  for (int kk = 0; kk < NN; kk += 32) {
    const float4 a00 = *(const float4*)(Wg + ga0 + kk);
    const float4 a01 = *(const float4*)(Wg + ga0 + kk + 4);
    const float4 a10 = *(const float4*)(Wg + ga1 + kk);
    const float4 a11 = *(const float4*)(Wg + ga1 + kk + 4);
    const uint4 wA0 = make_uint4(pack2(a00.x, a00.y), pack2(a00.z, a00.w),
                                 pack2(a01.x, a01.y), pack2(a01.z, a01.w));
    const uint4 wA1 = make_uint4(pack2(a10.x, a10.y), pack2(a10.z, a10.w),
                                 pack2(a11.x, a11.y), pack2(a11.z, a11.w));
    __syncthreads();
    gl_lds16(Bs + gb0 + kk, lS0);
    gl_lds16(Bs + gb1 + kk, lS1);
    gl_lds16(Bd + gb0 + kk, lD0);
    gl_lds16(Bd + gb1 + kk, lD1);
    *(uint4*)(sA + e0 * 8) = wA0;
    *(uint4*)(sA + e1 * 8) = wA1;
    __syncthreads();

    bf16x8 a[4], aa[4];
#pragma unroll
    for (int f = 0; f < 4; ++f) {
      short8 as = *(const short8*)(sA + (wm + f * 16 + lr) * 32 + q * 8);
      a[f]  = __builtin_bit_cast(bf16x8, as);
      aa[f] = __builtin_bit_cast(bf16x8, (short8)(as & msk));
    }
#pragma unroll
    for (int g = 0; g < 4; ++g) {
      bf16x8 bs = *(const bf16x8*)(sBs + (wn + g * 16 + lr) * 32 + q * 8);
      bf16x8 bd = *(const bf16x8*)(sBd + (wn + g * 16 + lr) * 32 + q * 8);
#pragma unroll
      for (int f = 0; f < 4; ++f) {
        accS[f][g] = __builtin_amdgcn_mfma_f32_16x16x32_bf16(a[f],  bs, accS[f][g], 0, 0, 0);
        accD[f][g] = __builtin_amdgcn_mfma_f32_16x16x32_bf16(aa[f], bd, accD[f][g], 0, 0, 0);
      }
    }
  }

  if (MODE == 0) {
    epi_write(accS, accD, outU, outL, i0, j0, jbase, wm, wn, lr, q);
  } else {
    epi_reduce(accS, accD, pub, plb, accUv, accLv, i0, j0, jbase, wm, wn, lr, q);
  }
}

// ---------------------------------------------------------------------------
// Six fused matvecs in one read of W (fp32).
// ---------------------------------------------------------------------------
__device__ __forceinline__ void load16(const float* p, float* f) {
  const float4* q4 = (const float4*)p;
#pragma unroll
  for (int i = 0; i < 4; ++i) {
    const float4 v = q4[i];
    f[4*i] = v.x; f[4*i+1] = v.y; f[4*i+2] = v.z; f[4*i+3] = v.w;
  }
}

__global__ __launch_bounds__(256)
void matvec6(const float* __restrict__ Wg, const float* __restrict__ bvec,
             const float* __restrict__ pbu,  const float* __restrict__ pbl,
             const float* __restrict__ pbu2, const float* __restrict__ pbl2,
             const float* __restrict__ pub,  const float* __restrict__ plb,
             float* __restrict__ out_bu, float* __restrict__ out_bl,
             float* __restrict__ bounds,
             float* __restrict__ bu_f, float* __restrict__ bl_f) {
  const int row = blockIdx.x;
  const int t   = threadIdx.x;
  const int c0  = t * 16;
  float w[16], xu[16], xl[16], x2u[16], x2l[16], uu[16], ul[16];
  load16(Wg + (size_t)row * NN + c0, w);
  load16(pbu  + c0, xu);  load16(pbl  + c0, xl);
  load16(pbu2 + c0, x2u); load16(pbl2 + c0, x2l);
  load16(pub  + c0, uu);  load16(plb  + c0, ul);
  float a_bu = 0, a_bl = 0, a_ub = 0, a_lb = 0, a_2u = 0, a_2l = 0;
#pragma unroll
  for (int i = 0; i < 16; ++i) {
    const float wp = fmaxf(w[i], 0.f), wm = fminf(w[i], 0.f);
    a_bu += wp * xu[i]  + wm * xl[i];
    a_bl += wp * xl[i]  + wm * xu[i];
    a_ub += wp * uu[i]  + wm * ul[i];
    a_lb += wp * ul[i]  + wm * uu[i];
    a_2u += wp * x2u[i] + wm * x2l[i];
    a_2l += wp * x2l[i] + wm * x2u[i];
  }
#pragma unroll
  for (int off = 32; off; off >>= 1) {
    a_bu += __shfl_down(a_bu, off, 64);
    a_bl += __shfl_down(a_bl, off, 64);
    a_ub += __shfl_down(a_ub, off, 64);
    a_lb += __shfl_down(a_lb, off, 64);
    a_2u += __shfl_down(a_2u, off, 64);
    a_2l += __shfl_down(a_2l, off, 64);
  }
  __shared__ float red[4][6];
  const int lane = t & 63, wvv = t >> 6;
  if (lane == 0) {
    red[wvv][0] = a_bu; red[wvv][1] = a_bl; red[wvv][2] = a_ub;
    red[wvv][3] = a_lb; red[wvv][4] = a_2u; red[wvv][5] = a_2l;
  }
  __syncthreads();
  if (t == 0) {
    float r0=0, r1=0, r2=0, r3=0, r4=0, r5=0;
    for (int v = 0; v < 4; ++v) {
      r0 += red[v][0]; r1 += red[v][1]; r2 += red[v][2];
      r3 += red[v][3]; r4 += red[v][4]; r5 += red[v][5];
    }
    const float bb = bvec[row];
    out_bu[row]      = r0 + bb;
    out_bl[row]      = r1 + bb;
    bounds[row]      = r2 + bb;   // ub
    bounds[NN + row] = r3 + bb;   // lb
    bu_f[row]        = r4 + bb;
    bl_f[row]        = r5 + bb;
  }
}

// ---------------------------------------------------------------------------
__global__ __launch_bounds__(256)
void finalize_bounds(const float* __restrict__ accU, const float* __restrict__ accL,
                     const float* __restrict__ bu_f, const float* __restrict__ bl_f,
                     float* __restrict__ bounds) {
  const int i = blockIdx.x * 256 + threadIdx.x;
  if (i >= NN) return;
  const float ub  = bounds[i];
  const float lb  = bounds[NN + i];
  const float ub2 = accU[i] + bu_f[i];
  const float lb2 = accL[i] + bl_f[i];
  bounds[2 * NN + i] = fminf(ub, ub2);
  bounds[3 * NN + i] = fmaxf(lb, lb2);
}

// ---------------------------------------------------------------------------
extern "C" void kernel_launch(void* const* d_in, const int* in_sizes, int n_in,
                              void* d_out, int out_size, void* d_ws, size_t ws_size,
                              hipStream_t stream) {
  const float* W    = (const float*)d_in[0];
  const float* b    = (const float*)d_in[1];
  const float* pWu  = (const float*)d_in[2];
  const float* pWl  = (const float*)d_in[3];
  const float* pbu  = (const float*)d_in[4];
  const float* pbl  = (const float*)d_in[5];
  const float* pWu2 = (const float*)d_in[6];
  const float* pWl2 = (const float*)d_in[7];
  const float* pbu2 = (const float*)d_in[8];
  const float* pbl2 = (const float*)d_in[9];
  const float* pub  = (const float*)d_in[10];
  const float* plb  = (const float*)d_in[11];

  float* out    = (float*)d_out;
  float* bounds = out;                          // [4, N]
  float* Wup    = out + 4 * NN;                 // [N, N]
  float* Wlo    = Wup + (size_t)NN * NN;        // [N, N]
  float* b_up   = Wlo + (size_t)NN * NN;        // [N]
  float* b_lo   = b_up + NN;                    // [N]

  // --- small ws header: 64 KB ---
  float* accU = (float*)d_ws;                   // N fp32
  float* accL = accU + NN;
  float* bu_f = accL + NN;
  float* bl_f = bu_f + NN;
  const size_t hdr = 65536;
  const size_t WBF = (size_t)NN * NN;           // elements of bf16 W

  (void)hipMemsetAsync(accU, 0, 2 * NN * sizeof(float), stream);

  // Fast path: ws holds Wbf (bf16 W, 32 MB) + S/D panels. Pick smallest P.
  int Pf = 1;
  while (Pf < 32 && hdr + 2 * WBF + 2 * ((size_t)NN / Pf) * NN * 2 > ws_size) Pf *= 2;
  const bool fast = (hdr + 2 * WBF + 2 * ((size_t)NN / Pf) * NN * 2 <= ws_size);

  if (fast) {
    uint16_t* Wbf = (uint16_t*)((char*)d_ws + hdr);
    const int NPf = NN / Pf;
    uint16_t* Sp = Wbf + WBF;
    uint16_t* Dp = Sp + (size_t)NPf * NN;

    wcvt<<<dim3(8192), 256, 0, stream>>>(W, Wbf);

    // --- GEMM2: bf16 scratch in d_out's Wup/Wlo regions (overwritten later)
    tp_sumdiff<<<dim3(64, 64), 256, 0, stream>>>(pWu2, pWl2,
                                                 (uint16_t*)Wup, (uint16_t*)Wlo, 0);
    gemm8p<1><<<dim3(32, 16), 512, 0, stream>>>(Wbf, (uint16_t*)Wup, (uint16_t*)Wlo,
                                                nullptr, nullptr,
                                                pub, plb, accU, accL, 0);

    // --- GEMM1: panelized over columns, scratch in ws after Wbf ---
    for (int p = 0; p < Pf; ++p) {
      const int jb = p * NPf;
      tp_sumdiff<<<dim3(NPf / 64, 64), 256, 0, stream>>>(pWu, pWl, Sp, Dp, jb);
      gemm8p<0><<<dim3(NPf / 128, 16), 512, 0, stream>>>(Wbf, Sp, Dp, Wup, Wlo,
                                                         nullptr, nullptr,
                                                         nullptr, nullptr, jb);
    }
  } else {
    // Fallback: fp32-A staging path; panels sized to fit ws.
    int P = 1;
    while (P < 32 && hdr + 2 * ((size_t)NN / P) * NN * 2 > ws_size) P *= 2;
    const int NP = NN / P;
    uint16_t* big = (uint16_t*)((char*)d_ws + hdr);
    uint16_t* Sp = big;
    uint16_t* Dp = big + (size_t)NP * NN;

    tp_sumdiff<<<dim3(64, 64), 256, 0, stream>>>(pWu2, pWl2,
                                                 (uint16_t*)Wup, (uint16_t*)Wlo, 0);
    gemm_fused<1><<<dim3(32, 32), 256, 0, stream>>>(W, (uint16_t*)Wup, (uint16_t*)Wlo,
                                                    nullptr, nullptr,
                                                    pub, plb, accU, accL, 0);
    for (int p = 0; p < P; ++p) {
      const int jb = p * NP;
      tp_sumdiff<<<dim3(NP / 64, 64), 256, 0, stream>>>(pWu, pWl, Sp, Dp, jb);
      gemm_fused<0><<<dim3(NP / 128, 32), 256, 0, stream>>>(W, Sp, Dp, Wup, Wlo,
                                                            nullptr, nullptr,
                                                            nullptr, nullptr, jb);
    }
  }

  matvec6<<<NN, 256, 0, stream>>>(W, b, pbu, pbl, pbu2, pbl2, pub, plb,
                                  b_up, b_lo, bounds, bu_f, bl_f);
  finalize_bounds<<<16, 256, 0, stream>>>(accU, accL, bu_f, bl_f, bounds);
}